// Round 6
// baseline (398.556 us; speedup 1.0000x reference)
//
#include <hip/hip_runtime.h>

// Problem constants (B=2, S=1024, D=1024, H=16, hd=64, L=4, M=12)
#define BATCH 2
#define SEQ   1024
#define DIM   1024
#define NH    16
#define HD    64
#define NM    12
#define NTOK  (BATCH*SEQ)          // 2048
#define MEMROWS (BATCH*SEQ*NM)     // 24576
#define OUTT  2097152              // elements per output tensor
#define NEGBIG (-1.0e30f)

typedef __attribute__((ext_vector_type(8))) short short8;   // 8 bf16 (4 VGPRs)
typedef __attribute__((ext_vector_type(4))) float f32x4;    // MFMA C/D

__device__ __forceinline__ float bf2f(ushort u) {
    union { unsigned int i; float f; } t; t.i = ((unsigned int)u) << 16; return t.f;
}
__device__ __forceinline__ ushort f2bf(float f) {
    union { float f; unsigned int i; } t; t.f = f;
    unsigned int i = t.i;
    unsigned int lsb = (i >> 16) & 1u;
    i += 0x7fffu + lsb;
    return (ushort)(i >> 16);
}

// ---------------------------------------------------------------------------
// fp32 -> bf16 conversion for x, Wqkv, Wout (one pass, float4-vectorized)
// ---------------------------------------------------------------------------
__global__ __launch_bounds__(256) void cvt3_kernel(
    const float* __restrict__ a, ushort* __restrict__ ab, int na4,
    const float* __restrict__ b, ushort* __restrict__ bb, int nb4,
    const float* __restrict__ c, ushort* __restrict__ cb, int nc4)
{
    int i = blockIdx.x * 256 + threadIdx.x;
    if (i >= na4 + nb4 + nc4) return;
    const float* src; ushort* dst; int j;
    if (i < na4)            { src = a; dst = ab; j = i; }
    else if (i < na4 + nb4) { src = b; dst = bb; j = i - na4; }
    else                    { src = c; dst = cb; j = i - na4 - nb4; }
    float4 v = ((const float4*)src)[j];
    ushort4 o; o.x = f2bf(v.x); o.y = f2bf(v.y); o.z = f2bf(v.z); o.w = f2bf(v.w);
    ((ushort4*)dst)[j] = o;
}

// ---------------------------------------------------------------------------
// MFMA GEMM core conventions (verified):
//  A-frag: m=lane&15, k=qd*8+j ; B-frag: n=lane&15, k=qd*8+j
//  C/D:    col=lane&15, row=qd*4+reg
// LDS tiles padded to 40/72 elems/row.
// ---------------------------------------------------------------------------

// ---------------------------------------------------------------------------
// FUSED qkv GEMM + LayerNorm(mem rows) — heterogeneous blocks.
// Blocks 0..383: qkv GEMM. Blocks 384..6527: LN of 4 mem rows each.
// (R4: 73.7us fused vs ~87us serial; ln's ~2.1TB/s access-pattern wall is
//  hidden under the GEMM's MFMA time.)
// ---------------------------------------------------------------------------
#define QKV_BLKS 384
__global__ __launch_bounds__(256) void qkv_ln_fused_kernel(
    const ushort* __restrict__ xb, const ushort* __restrict__ Wb,
    const float* __restrict__ bias, float* __restrict__ out,
    ushort* __restrict__ qkvb,
    const float* __restrict__ pq, const float* __restrict__ pk,
    const float* __restrict__ pv, ushort* __restrict__ mem_n)
{
    const int bid = blockIdx.x;
    const int tid = threadIdx.x;
    if (bid < QKV_BLKS) {
        // ---------------- qkv GEMM path ----------------
        __shared__ ushort As[128][40];
        __shared__ ushort Bs[128][40];
        const int w = tid >> 6, lane = tid & 63;
        const int n = lane & 15, qd = lane >> 4;
        const int wr = (w >> 1) * 64, wc = (w & 1) * 64;
        const int row0 = (bid / 24) * 128, col0 = (bid % 24) * 128;
        const int r1 = tid >> 2, o1 = (tid & 3) * 8;
        const int r2 = (tid + 256) >> 2, o2 = ((tid + 256) & 3) * 8;

        f32x4 acc[4][4];
#pragma unroll
        for (int mt = 0; mt < 4; mt++)
#pragma unroll
            for (int nt = 0; nt < 4; nt++) acc[mt][nt] = (f32x4){0.f, 0.f, 0.f, 0.f};

        for (int k0 = 0; k0 < 1024; k0 += 32) {
            *(short8*)&As[r1][o1] = *(const short8*)(xb + (size_t)(row0 + r1) * 1024 + k0 + o1);
            *(short8*)&As[r2][o2] = *(const short8*)(xb + (size_t)(row0 + r2) * 1024 + k0 + o2);
            *(short8*)&Bs[r1][o1] = *(const short8*)(Wb + (size_t)(col0 + r1) * 1024 + k0 + o1);
            *(short8*)&Bs[r2][o2] = *(const short8*)(Wb + (size_t)(col0 + r2) * 1024 + k0 + o2);
            __syncthreads();
            short8 af[4], bf[4];
#pragma unroll
            for (int mt = 0; mt < 4; mt++) af[mt] = *(const short8*)&As[wr + mt * 16 + n][qd * 8];
#pragma unroll
            for (int nt = 0; nt < 4; nt++) bf[nt] = *(const short8*)&Bs[wc + nt * 16 + n][qd * 8];
#pragma unroll
            for (int mt = 0; mt < 4; mt++)
#pragma unroll
                for (int nt = 0; nt < 4; nt++)
                    acc[mt][nt] = __builtin_amdgcn_mfma_f32_16x16x32_bf16(af[mt], bf[nt], acc[mt][nt], 0, 0, 0);
            __syncthreads();
        }
#pragma unroll
        for (int mt = 0; mt < 4; mt++)
#pragma unroll
            for (int nt = 0; nt < 4; nt++)
#pragma unroll
                for (int r = 0; r < 4; r++) {
                    int row = row0 + wr + mt * 16 + qd * 4 + r;
                    int col = col0 + wc + nt * 16 + n;
                    float val = acc[mt][nt][r] + bias[col];
                    int t = col >> 10, h = (col >> 6) & 15, d = col & 63;
                    int b = row >> 10, s = row & 1023;
                    size_t idx = (((size_t)(b * NH + h) * SEQ + s) * HD) + d;
                    size_t base = (t == 0) ? (size_t)3 * OUTT : (t == 1) ? (size_t)OUTT : (size_t)2 * OUTT;
                    out[base + idx] = val;
                    qkvb[(size_t)t * OUTT + idx] = f2bf(val);
                }
    } else {
        // ---------------- LayerNorm path (wave per row) ----------------
        const int wid = tid >> 6, lane = tid & 63;
        const int r = (bid - QKV_BLKS) * 4 + wid;   // mem row 0..24575
        const int idx = r % NM;
        const int bs = r / NM;
        const int s = bs & (SEQ - 1);
        const int b = bs >> 10;
        const int c = idx >> 2;                  // 0=q 1=k 2=v
        const int l = idx & 3;                   // layer
        const float* src = (c == 0) ? pq : ((c == 1) ? pk : pv);
        const size_t base = ((size_t)(l * BATCH + b) * NH) * (SEQ * HD) + (size_t)s * HD;

        float4 v4[4];
        float sum = 0.f, sumsq = 0.f;
#pragma unroll
        for (int p = 0; p < 4; p++) {
            int h = p * 4 + (lane >> 4);
            int d = (lane & 15) * 4;
            float4 v = *(const float4*)(src + base + (size_t)h * (SEQ * HD) + d);
            v4[p] = v;
            sum   += v.x + v.y + v.z + v.w;
            sumsq += v.x * v.x + v.y * v.y + v.z * v.z + v.w * v.w;
        }
#pragma unroll
        for (int off = 32; off > 0; off >>= 1) {
            sum   += __shfl_xor(sum, off);
            sumsq += __shfl_xor(sumsq, off);
        }
        float mu  = sum * (1.f / 1024.f);
        float var = fmaxf(sumsq * (1.f / 1024.f) - mu * mu, 0.f);
        float inv = rsqrtf(var + 1e-5f);
        ushort* dst = mem_n + (size_t)r * 1024;
#pragma unroll
        for (int p = 0; p < 4; p++) {
            int dp = (p * 64 + lane) * 4;
            ushort4 o;
            o.x = f2bf((v4[p].x - mu) * inv);
            o.y = f2bf((v4[p].y - mu) * inv);
            o.z = f2bf((v4[p].z - mu) * inv);
            o.w = f2bf((v4[p].w - mu) * inv);
            *(ushort4*)(dst + dp) = o;
        }
    }
}

// out GEMM: mergedb[2048x1024] x Woutb[1024x1024]^T + bout -> d_out fp32
__global__ __launch_bounds__(256) void mfma_out_kernel(
    const ushort* __restrict__ Ab, const ushort* __restrict__ Wb,
    const float* __restrict__ bias, float* __restrict__ C)
{
    __shared__ ushort As[128][40];
    __shared__ ushort Bs[128][40];
    const int tid = threadIdx.x;
    const int w = tid >> 6, lane = tid & 63;
    const int n = lane & 15, qd = lane >> 4;
    const int wr = (w >> 1) * 64, wc = (w & 1) * 64;
    const int row0 = blockIdx.y * 128, col0 = blockIdx.x * 128;
    const int r1 = tid >> 2, o1 = (tid & 3) * 8;
    const int r2 = (tid + 256) >> 2, o2 = ((tid + 256) & 3) * 8;

    f32x4 acc[4][4];
#pragma unroll
    for (int mt = 0; mt < 4; mt++)
#pragma unroll
        for (int nt = 0; nt < 4; nt++) acc[mt][nt] = (f32x4){0.f, 0.f, 0.f, 0.f};

    for (int k0 = 0; k0 < 1024; k0 += 32) {
        *(short8*)&As[r1][o1] = *(const short8*)(Ab + (size_t)(row0 + r1) * 1024 + k0 + o1);
        *(short8*)&As[r2][o2] = *(const short8*)(Ab + (size_t)(row0 + r2) * 1024 + k0 + o2);
        *(short8*)&Bs[r1][o1] = *(const short8*)(Wb + (size_t)(col0 + r1) * 1024 + k0 + o1);
        *(short8*)&Bs[r2][o2] = *(const short8*)(Wb + (size_t)(col0 + r2) * 1024 + k0 + o2);
        __syncthreads();
        short8 af[4], bf[4];
#pragma unroll
        for (int mt = 0; mt < 4; mt++) af[mt] = *(const short8*)&As[wr + mt * 16 + n][qd * 8];
#pragma unroll
        for (int nt = 0; nt < 4; nt++) bf[nt] = *(const short8*)&Bs[wc + nt * 16 + n][qd * 8];
#pragma unroll
        for (int mt = 0; mt < 4; mt++)
#pragma unroll
            for (int nt = 0; nt < 4; nt++)
                acc[mt][nt] = __builtin_amdgcn_mfma_f32_16x16x32_bf16(af[mt], bf[nt], acc[mt][nt], 0, 0, 0);
        __syncthreads();
    }
#pragma unroll
    for (int mt = 0; mt < 4; mt++)
#pragma unroll
        for (int nt = 0; nt < 4; nt++)
#pragma unroll
            for (int r = 0; r < 4; r++) {
                int row = row0 + wr + mt * 16 + qd * 4 + r;
                int col = col0 + wc + nt * 16 + n;
                C[(size_t)row * 1024 + col] = acc[mt][nt][r] + bias[col];
            }
}

// vproj per head: merged[t, h*64+d] += wvec_h[t,:]·Wv[h*64+d,:] + wsum*bv (in-place bf16)
__global__ __launch_bounds__(256) void mfma_vproj_kernel(
    const ushort* __restrict__ wvecb, const ushort* __restrict__ Wvb,
    const float* __restrict__ bv, const float* __restrict__ wmem,
    ushort* __restrict__ mergedb)
{
    __shared__ ushort As[128][40];
    __shared__ ushort Bs[64][40];
    const int tid = threadIdx.x;
    const int w = tid >> 6, lane = tid & 63;
    const int n = lane & 15, qd = lane >> 4;
    const int wr = (w >> 1) * 64, wc = (w & 1) * 32;
    const int row0 = blockIdx.x * 128;
    const int h = blockIdx.y;
    const int r1 = tid >> 2, o1 = (tid & 3) * 8;
    const int r2 = (tid + 256) >> 2, o2 = ((tid + 256) & 3) * 8;

    f32x4 acc[4][2];
#pragma unroll
    for (int mt = 0; mt < 4; mt++)
#pragma unroll
        for (int nt = 0; nt < 2; nt++) acc[mt][nt] = (f32x4){0.f, 0.f, 0.f, 0.f};

    for (int k0 = 0; k0 < 1024; k0 += 32) {
        *(short8*)&As[r1][o1] = *(const short8*)(wvecb + ((size_t)(row0 + r1) * NH + h) * 1024 + k0 + o1);
        *(short8*)&As[r2][o2] = *(const short8*)(wvecb + ((size_t)(row0 + r2) * NH + h) * 1024 + k0 + o2);
        *(short8*)&Bs[r1 & 63][o1] = *(const short8*)(Wvb + (size_t)(h * HD + (r1 & 63)) * 1024 + k0 + o1);
        __syncthreads();
        short8 af[4], bf[2];
#pragma unroll
        for (int mt = 0; mt < 4; mt++) af[mt] = *(const short8*)&As[wr + mt * 16 + n][qd * 8];
#pragma unroll
        for (int nt = 0; nt < 2; nt++) bf[nt] = *(const short8*)&Bs[wc + nt * 16 + n][qd * 8];
#pragma unroll
        for (int mt = 0; mt < 4; mt++)
#pragma unroll
            for (int nt = 0; nt < 2; nt++)
                acc[mt][nt] = __builtin_amdgcn_mfma_f32_16x16x32_bf16(af[mt], bf[nt], acc[mt][nt], 0, 0, 0);
        __syncthreads();
    }
#pragma unroll
    for (int mt = 0; mt < 4; mt++)
#pragma unroll
        for (int nt = 0; nt < 2; nt++)
#pragma unroll
            for (int r = 0; r < 4; r++) {
                int token = row0 + wr + mt * 16 + qd * 4 + r;
                int d = wc + nt * 16 + n;
                float ws = wmem[((size_t)token * NH + h) * 16 + 12];
                size_t mi = (size_t)token * DIM + h * HD + d;
                float val = bf2f(mergedb[mi]) + acc[mt][nt][r] + ws * bv[h * HD + d];
                mergedb[mi] = f2bf(val);
            }
}

// ---------------------------------------------------------------------------
// msc_direct: FUSED qproj + mem_scores. Eliminates the 67MB qproj HBM
// intermediate (write+read = 134MB). 256 blocks x 8 tokens x 4 waves.
// Per 64-col chunk:
//   1. stage mem rows chunk (only unavoidable traffic, read once total)
//   2. per wave (4 heads each): transpose-stage Wk col-slice (wave-private
//      LDS, same-wave lgkmcnt ordering, no barrier), MFMA#1 computes
//      qproj chunk -> bf16 LDS
//   3. barrier; MFMA#2 per token contracts qproj-chunk x mem-chunk into
//      persistent (h x m) accumulator (same frag mapping as verified msc).
// Numerics identical to old qproj->msc path (f2bf between the two MFMAs).
// ---------------------------------------------------------------------------
#define MSC_T 8
__global__ __launch_bounds__(256) void msc_direct_kernel(
    const ushort* __restrict__ qkvb, const ushort* __restrict__ mem_n,
    const ushort* __restrict__ Wkb, const float* __restrict__ bqkv,
    float* __restrict__ msc)
{
    __shared__ ushort qs[MSC_T][16][72];     // [t][h][d]     18.4 KB
    __shared__ ushort memc[MSC_T][12][72];   // [t][m][c]     13.8 KB
    __shared__ ushort qpc[MSC_T][16][72];    // [t][h][c]     18.4 KB
    __shared__ ushort wks[4][64][72];        // per-wave [c][k] 36.9 KB
    __shared__ float  qbkL[MSC_T][16];

    const int tid = threadIdx.x;
    const int w = tid >> 6, lane = tid & 63;
    const int n = lane & 15, qd = lane >> 4;
    const int t0 = blockIdx.x * MSC_T;

    // prologue: stage q rows for 8 tokens x 16 heads
    {
        const int rid = tid >> 1, half = tid & 1;
        const int t = rid >> 4, h = rid & 15;
        const int g = t0 + t, b = g >> 10, s = g & 1023;
        const ushort* src = qkvb + (((size_t)(b * NH + h) * SEQ + s) * HD) + half * 32;
        *(short8*)&qs[t][h][half * 32]      = *(const short8*)(src);
        *(short8*)&qs[t][h][half * 32 + 8]  = *(const short8*)(src + 8);
        *(short8*)&qs[t][h][half * 32 + 16] = *(const short8*)(src + 16);
        *(short8*)&qs[t][h][half * 32 + 24] = *(const short8*)(src + 24);
    }
    __syncthreads();
    if (tid < 128) {
        const int t = tid >> 4, h = tid & 15;
        const float* bk = bqkv + DIM + h * HD;
        float s = 0.f;
#pragma unroll
        for (int d = 0; d < HD; d++) s += bf2f(qs[t][h][d]) * bk[d];
        qbkL[t][h] = s;
    }
    // qbkL read only in epilogue; chunk-loop barriers guarantee visibility.

    f32x4 acc[2];
    acc[0] = (f32x4){0.f, 0.f, 0.f, 0.f};
    acc[1] = (f32x4){0.f, 0.f, 0.f, 0.f};

    for (int ch = 0; ch < 16; ch++) {
        const int c0 = ch * 64;
        __syncthreads();   // memc/qpc overwrite vs previous chunk's readers
        // 1. stage memc: 96 rows (t,m) x 64 c
#pragma unroll
        for (int i = 0; i < 3; i++) {
            int sid = i * 256 + tid;
            int row = sid >> 3, o8 = (sid & 7) * 8;
            int t = row / 12, m = row % 12;
            *(short8*)&memc[t][m][o8] =
                *(const short8*)(mem_n + ((size_t)(t0 + t) * NM + m) * 1024 + c0 + o8);
        }
        // 2. per-wave: 4 heads each
#pragma unroll
        for (int hh = 0; hh < 4; hh++) {
            const int h = w * 4 + hh;
            // transpose-stage: wks[w][c][lane] = Wk[h*64+lane][c0+c]
            const ushort* wsrc = Wkb + (size_t)(h * HD + lane) * 1024 + c0;
#pragma unroll
            for (int j = 0; j < 4; j++) {
                ushort t16[16];
                *(short8*)&t16[0] = *(const short8*)(wsrc + j * 16);
                *(short8*)&t16[8] = *(const short8*)(wsrc + j * 16 + 8);
#pragma unroll
                for (int c = 0; c < 16; c++) wks[w][j * 16 + c][lane] = t16[c];
            }
            // MFMA#1: D[token, c] = q[token,:] @ Wk_h^T  (tokens 8..15 dup/discard)
            short8 af0 = *(const short8*)&qs[n & 7][h][qd * 8];
            short8 af1 = *(const short8*)&qs[n & 7][h][32 + qd * 8];
#pragma unroll
            for (int nt = 0; nt < 4; nt++) {
                short8 bf0 = *(const short8*)&wks[w][nt * 16 + n][qd * 8];
                short8 bf1 = *(const short8*)&wks[w][nt * 16 + n][32 + qd * 8];
                f32x4 z = (f32x4){0.f, 0.f, 0.f, 0.f};
                z = __builtin_amdgcn_mfma_f32_16x16x32_bf16(af0, bf0, z, 0, 0, 0);
                z = __builtin_amdgcn_mfma_f32_16x16x32_bf16(af1, bf1, z, 0, 0, 0);
                if (qd < 2) {
#pragma unroll
                    for (int r = 0; r < 4; r++)
                        qpc[qd * 4 + r][h][nt * 16 + n] = f2bf(z[r]);
                }
            }
        }
        __syncthreads();
        // 3. MFMA#2: per token, msc[h][m] += qproj_chunk . mem_chunk
#pragma unroll
        for (int p = 0; p < 2; p++) {
            const int tw = w + p * 4;
            const int mrow = (n < NM) ? n : 0;
            short8 af0 = *(const short8*)&qpc[tw][n][qd * 8];
            short8 af1 = *(const short8*)&qpc[tw][n][32 + qd * 8];
            short8 bf0 = *(const short8*)&memc[tw][mrow][qd * 8];
            short8 bf1 = *(const short8*)&memc[tw][mrow][32 + qd * 8];
            acc[p] = __builtin_amdgcn_mfma_f32_16x16x32_bf16(af0, bf0, acc[p], 0, 0, 0);
            acc[p] = __builtin_amdgcn_mfma_f32_16x16x32_bf16(af1, bf1, acc[p], 0, 0, 0);
        }
    }
    // epilogue
    if (n < NM) {
#pragma unroll
        for (int p = 0; p < 2; p++) {
            const int tw = w + p * 4;
            const size_t gt = t0 + tw;
#pragma unroll
            for (int r = 0; r < 4; r++) {
                int h = qd * 4 + r;
                msc[(gt * NH + h) * NM + n] = 0.125f * (acc[p][r] + qbkL[tw][h]);
            }
        }
    }
}

// ---------------------------------------------------------------------------
// Flash attention (MFMA bf16), 8-wave split-KV.
// ---------------------------------------------------------------------------
#define TQ 64
#define TK 64
__global__ __launch_bounds__(512) void flash_attn_kernel(
    const ushort* __restrict__ qkvb, const float* __restrict__ msc,
    ushort* __restrict__ mergedb, float* __restrict__ wmem)
{
    // 55296 B total: Ks[2][64][72] | Vt[2][64][72] | Ps[8][16][72]
    // cbuf (combine, 4x64x25 f32 = 25600 B) aliases Ks/Vt after the KV loop.
    __shared__ __align__(16) char smem[55296];
    ushort (*Ks)[TK][72]  = (ushort (*)[TK][72])smem;
    ushort (*Vt)[HD][72]  = (ushort (*)[HD][72])(smem + 18432);
    ushort (*Ps)[16][72]  = (ushort (*)[16][72])(smem + 36864);
    float  (*cbuf)[64][25] = (float (*)[64][25])smem;

    const int bxr = blockIdx.x;
    const int qt = (bxr & 1) ? (bxr >> 1) : (15 - (bxr >> 1));
    const int bh = blockIdx.y;
    const int b = bh >> 4, h = bh & 15;
    const int tid = threadIdx.x;
    const int w = tid >> 6;        // 0..7
    const int g = w >> 2;          // kv parity group
    const int wq = w & 3;          // q sub-tile within the 64-row block
    const int lane = tid & 63;
    const int n = lane & 15;
    const int qd = lane >> 4;

    const ushort* qb = qkvb;
    const ushort* kb = qkvb + (size_t)OUTT;
    const ushort* vb = qkvb + (size_t)2 * OUTT;
    const size_t headoff = (size_t)bh * SEQ * HD;

    const int qrow0 = qt * TQ + wq * 16;
    const ushort* qp = qb + headoff + (size_t)(qrow0 + n) * HD;
    short8 qf0 = *(const short8*)(qp + qd * 8);
    short8 qf1 = *(const short8*)(qp + 32 + qd * 8);

    float mrow[4], lrow[4];
    f32x4 Oacc[4];
#pragma unroll
    for (int r = 0; r < 4; r++) { mrow[r] = NEGBIG; lrow[r] = 0.f; }
#pragma unroll
    for (int nt = 0; nt < 4; nt++) Oacc[nt] = (f32x4){0.f, 0.f, 0.f, 0.f};

    // staging indices within each 256-thread group
    const int gtid = tid & 255;
    const int key = gtid >> 2;
    const int c0 = (gtid & 3) * 16;
    const int nsteps = (qt + 2) >> 1;   // ceil((qt+1)/2)

    for (int step = 0; step < nsteps; ++step) {
        const int kt = 2 * step + g;
        const bool act = (kt <= qt);
        if (act) {
            const ushort* kg = kb + headoff + (size_t)(kt * TK + key) * HD + c0;
            *(short8*)&Ks[g][key][c0]     = *(const short8*)kg;
            *(short8*)&Ks[g][key][c0 + 8] = *(const short8*)(kg + 8);
            const ushort* vg = vb + headoff + (size_t)(kt * TK + key) * HD + c0;
            ushort vs[16];
            *(short8*)&vs[0] = *(const short8*)vg;
            *(short8*)&vs[8] = *(const short8*)(vg + 8);
#pragma unroll
            for (int i = 0; i < 16; i++) Vt[g][c0 + i][key] = vs[i];
        }
        __syncthreads();
        if (act) {
            f32x4 sacc[4];
#pragma unroll
            for (int kc = 0; kc < 4; kc++) {
                short8 kf0 = *(const short8*)&Ks[g][kc * 16 + n][qd * 8];
                short8 kf1 = *(const short8*)&Ks[g][kc * 16 + n][32 + qd * 8];
                f32x4 z = (f32x4){0.f, 0.f, 0.f, 0.f};
                z = __builtin_amdgcn_mfma_f32_16x16x32_bf16(qf0, kf0, z, 0, 0, 0);
                z = __builtin_amdgcn_mfma_f32_16x16x32_bf16(qf1, kf1, z, 0, 0, 0);
                sacc[kc] = z;
            }
            const bool diag = (kt == qt);
#pragma unroll
            for (int kc = 0; kc < 4; kc++) {
#pragma unroll
                for (int r = 0; r < 4; r++) {
                    float sv = sacc[kc][r] * 0.125f;
                    if (diag) {
                        int qrow = qrow0 + qd * 4 + r;
                        int kk = kt * TK + kc * 16 + n;
                        if (kk > qrow) sv = NEGBIG;
                    }
                    sacc[kc][r] = sv;
                }
            }
            float alpha[4];
#pragma unroll
            for (int r = 0; r < 4; r++) {
                float mx = fmaxf(fmaxf(sacc[0][r], sacc[1][r]), fmaxf(sacc[2][r], sacc[3][r]));
                mx = fmaxf(mx, __shfl_xor(mx, 1));
                mx = fmaxf(mx, __shfl_xor(mx, 2));
                mx = fmaxf(mx, __shfl_xor(mx, 4));
                mx = fmaxf(mx, __shfl_xor(mx, 8));
                float mnew = fmaxf(mrow[r], mx);
                alpha[r] = __expf(mrow[r] - mnew);
                mrow[r] = mnew;
            }
            float psum[4] = {0.f, 0.f, 0.f, 0.f};
#pragma unroll
            for (int kc = 0; kc < 4; kc++) {
#pragma unroll
                for (int r = 0; r < 4; r++) {
                    float p = __expf(sacc[kc][r] - mrow[r]);
                    psum[r] += p;
                    Ps[w][qd * 4 + r][kc * 16 + n] = f2bf(p);
                }
            }
#pragma unroll
            for (int r = 0; r < 4; r++) {
                float ps = psum[r];
                ps += __shfl_xor(ps, 1);
                ps += __shfl_xor(ps, 2);
                ps += __shfl_xor(ps, 4);
                ps += __shfl_xor(ps, 8);
                lrow[r] = alpha[r] * lrow[r] + ps;
            }
#pragma unroll
            for (int nt = 0; nt < 4; nt++)
#pragma unroll
                for (int r = 0; r < 4; r++)
                    Oacc[nt][r] *= alpha[r];
            short8 pf0 = *(const short8*)&Ps[w][n][qd * 8];
            short8 pf1 = *(const short8*)&Ps[w][n][32 + qd * 8];
#pragma unroll
            for (int nt = 0; nt < 4; nt++) {
                short8 vf0 = *(const short8*)&Vt[g][nt * 16 + n][qd * 8];
                short8 vf1 = *(const short8*)&Vt[g][nt * 16 + n][32 + qd * 8];
                f32x4 z = Oacc[nt];
                z = __builtin_amdgcn_mfma_f32_16x16x32_bf16(pf0, vf0, z, 0, 0, 0);
                z = __builtin_amdgcn_mfma_f32_16x16x32_bf16(pf1, vf1, z, 0, 0, 0);
                Oacc[nt] = z;
            }
        }
        __syncthreads();
    }

    // --- two-way combine: group 1 hands its state to group 0 via LDS ---
    if (g == 1) {
        float* cb = cbuf[wq][lane];
#pragma unroll
        for (int nt = 0; nt < 4; nt++)
#pragma unroll
            for (int r = 0; r < 4; r++) cb[nt * 4 + r] = Oacc[nt][r];
#pragma unroll
        for (int r = 0; r < 4; r++) { cb[16 + r] = mrow[r]; cb[20 + r] = lrow[r]; }
    }
    __syncthreads();
    if (g == 1) return;

    {
        const float* cb = cbuf[wq][lane];
#pragma unroll
        for (int r = 0; r < 4; r++) {
            float m1 = cb[16 + r], l1 = cb[20 + r];
            float mnew = fmaxf(mrow[r], m1);
            float a0 = __expf(mrow[r] - mnew);
            float a1 = __expf(m1 - mnew);
            lrow[r] = a0 * lrow[r] + a1 * l1;
#pragma unroll
            for (int nt = 0; nt < 4; nt++)
                Oacc[nt][r] = a0 * Oacc[nt][r] + a1 * cb[nt * 4 + r];
            mrow[r] = mnew;
        }
    }

#pragma unroll
    for (int r = 0; r < 4; r++) {
        int srow = qrow0 + qd * 4 + r;
        const float* mp = msc + ((size_t)(b * SEQ + srow) * NH + h) * NM;
        float mm = NEGBIG;
#pragma unroll
        for (int j = 0; j < NM; j++) mm = fmaxf(mm, mp[j]);
        float mf = fmaxf(mrow[r], mm);
        float al = __expf(mrow[r] - mf);
        float msum = 0.f;
#pragma unroll
        for (int j = 0; j < NM; j++) msum += __expf(mp[j] - mf);
        float lf = al * lrow[r] + msum;
        float inv = 1.f / lf;
        float scale = al * inv;
        ushort* mrow_out = mergedb + (size_t)(b * SEQ + srow) * DIM + h * HD;
#pragma unroll
        for (int nt = 0; nt < 4; nt++)
            mrow_out[nt * 16 + n] = f2bf(Oacc[nt][r] * scale);
        size_t wb = ((size_t)(b * SEQ + srow) * NH + h) * 16;
        if (n < 12)       wmem[wb + n]  = __expf(mp[n] - mf) * inv;
        else if (n == 12) wmem[wb + 12] = msum * inv;
    }
}

// ---------------------------------------------------------------------------
// wvec[bs,h,:] = sum_m wmem[bs,h,m] * mem_n[bs,m,:]  (bf16 out)
// ---------------------------------------------------------------------------
__global__ __launch_bounds__(256) void wvec_kernel(
    const float* __restrict__ wmem, const ushort* __restrict__ mem_n,
    ushort* __restrict__ wvecb)
{
    __shared__ ushort memL[NM][1032];
    __shared__ float wL[NH][NM];
    const int bs = blockIdx.x;
    const int tid = threadIdx.x;

    for (int t = tid; t < NM * 256; t += 256) {
        int m = t >> 8, c4 = (t & 255) << 2;
        *(ushort4*)&memL[m][c4] = *(const ushort4*)(mem_n + ((size_t)bs * NM + m) * 1024 + c4);
    }
    if (tid < NH * NM) {
        int h = tid / NM, m = tid % NM;
        wL[h][m] = wmem[((size_t)bs * NH + h) * 16 + m];
    }
    __syncthreads();

    for (int h = 0; h < NH; h++) {
#pragma unroll
        for (int c0 = 0; c0 < 1024; c0 += 256) {
            int c = c0 + tid;
            float acc = 0.f;
#pragma unroll
            for (int m = 0; m < NM; m++)
                acc = fmaf(wL[h][m], bf2f(memL[m][c]), acc);
            wvecb[((size_t)bs * NH + h) * 1024 + c] = f2bf(acc);
        }
    }
}

// ---------------------------------------------------------------------------
extern "C" void kernel_launch(void* const* d_in, const int* in_sizes, int n_in,
                              void* d_out, int out_size, void* d_ws, size_t ws_size,
                              hipStream_t stream) {
    const float* x    = (const float*)d_in[0];
    const float* pk   = (const float*)d_in[1];
    const float* pv   = (const float*)d_in[2];
    const float* pq   = (const float*)d_in[3];
    const float* Wqkv = (const float*)d_in[4];
    const float* bqkv = (const float*)d_in[5];
    const float* Wout = (const float*)d_in[6];
    const float* bout = (const float*)d_in[7];
    float* out = (float*)d_out;

    // ws: mem_n 50.3 | wvecb 67.1 | msc 1.6 | wmem 2.1 |
    //     qkvb 12.6 | Wqkvb 6.3 | Woutb 2.1 | xb/mergedb 4.2 (aliased) ~146 MB
    ushort* mem_n  = (ushort*)d_ws;
    ushort* wvecb  = mem_n + (size_t)MEMROWS * 1024;
    float*  msc    = (float*)(wvecb + (size_t)NTOK * NH * 1024);
    float*  wmem   = msc + (size_t)NTOK * NH * NM;
    ushort* qkvb   = (ushort*)(wmem + (size_t)NTOK * NH * 16);
    ushort* Wqkvb  = qkvb + (size_t)3 * OUTT;
    ushort* Woutb  = Wqkvb + (size_t)3072 * 1024;
    ushort* xb     = Woutb + (size_t)1024 * 1024;
    ushort* mergedb = xb;                                   // alias: xb dead after qkv gemm

    const int na4 = NTOK * DIM / 4, nb4 = 3 * DIM * DIM / 4, nc4 = DIM * DIM / 4;

    // 1. bf16 conversions
    cvt3_kernel<<<(na4 + nb4 + nc4 + 255) / 256, 256, 0, stream>>>(
        x, xb, na4, Wqkv, Wqkvb, nb4, Wout, Woutb, nc4);
    // 2+3. FUSED: qkv GEMM (384 blocks) + layernorm of mem rows (6144 blocks).
    qkv_ln_fused_kernel<<<QKV_BLKS + MEMROWS / 4, 256, 0, stream>>>(
        xb, Wqkvb, bqkv, out, qkvb, pq, pk, pv, mem_n);
    // 4+5. FUSED: mem scores computed directly from q, Wk, mem_n
    //      (no 67MB qproj intermediate).
    msc_direct_kernel<<<NTOK / MSC_T, 256, 0, stream>>>(
        qkvb, mem_n, Wqkvb + (size_t)DIM * DIM, bqkv, msc);
    // 6. flash attention (8-wave split-KV) -> mergedb bf16, wmem
    flash_attn_kernel<<<dim3(16, 32), 512, 0, stream>>>(qkvb, msc, mergedb, wmem);
    // 7. wvec
    wvec_kernel<<<NTOK, 256, 0, stream>>>(wmem, mem_n, wvecb);
    // 8. vproj (MFMA, per head): mergedb += wvec@Wv^T + wsum*bv (in place)
    mfma_vproj_kernel<<<dim3(16, NH), 256, 0, stream>>>(
        wvecb, Wqkvb + (size_t)2 * DIM * DIM, bqkv + 2 * DIM, wmem, mergedb);
    // 9. out GEMM (MFMA) -> d_out fp32
    mfma_out_kernel<<<dim3(8, 16), 256, 0, stream>>>(mergedb, Woutb, bout, out);
}